// Round 8
// baseline (133.082 us; speedup 1.0000x reference)
//
#include <hip/hip_runtime.h>
#include <hip/hip_bf16.h>

// Problem constants (B=1)
#define CC   448   // channels
#define CGC  64    // key/query channels
#define MMM  7     // m groups
#define HWSZ 4096  // H*W
#define KK2  49    // K*K
#define GPH  32    // geometry-prior hidden

typedef __attribute__((ext_vector_type(8))) short   short8;   // 8 bf16 (4 VGPRs)
typedef __attribute__((ext_vector_type(4))) float   f32x4;
typedef __attribute__((ext_vector_type(4))) unsigned short us4;

__device__ __forceinline__ unsigned short f2b(float f) {
    union { __hip_bfloat16 h; unsigned short u; } cv;
    cv.h = __float2bfloat16(f);
    return cv.u;
}

// ---------------- Kernel 1: fused k+q GEMM ------------------------------
// C[128, 4096] = [Wk;Wq](128x448) @ x(448x4096). Tile 128x32, 256 thr = 4 waves.
__global__ __launch_bounds__(256) void kq_mfma(
    const float* __restrict__ x,
    const float* __restrict__ Wk, const float* __restrict__ bk,
    const float* __restrict__ Wq, const float* __restrict__ bq,
    float* __restrict__ km, float* __restrict__ qm)
{
    __shared__ unsigned short As[4096];   // 8 KB  [kg(4)][m(128)][j(8)]
    __shared__ unsigned short Bs[1024];   // 2 KB  [kg(4)][n(32)][j(8)]

    const int tid  = threadIdx.x;
    const int nT   = blockIdx.x * 32;
    const int lane = tid & 63;
    const int wid  = tid >> 6;
    const int wm   = wid * 32;
    const int l15  = lane & 15;
    const int l4   = lane >> 4;

    const int ar = tid >> 3;          // 0..31: A row within rep
    const int ak = tid & 7;           // which float4 of the 32-k chunk
    const int bkr = tid >> 3;         // 0..31: B k-row
    const int bn4 = tid & 7;          // 0..7: B float4 col group

    f32x4 acc[2][2];
    #pragma unroll
    for (int i = 0; i < 2; ++i)
        #pragma unroll
        for (int j = 0; j < 2; ++j)
            acc[i][j] = (f32x4){0.f, 0.f, 0.f, 0.f};

    float4 a0 = *(const float4*)(Wk + (size_t)ar * CC + ak * 4);
    float4 a1 = *(const float4*)(Wk + (size_t)(ar + 32) * CC + ak * 4);
    float4 a2 = *(const float4*)(Wq + (size_t)ar * CC + ak * 4);
    float4 a3 = *(const float4*)(Wq + (size_t)(ar + 32) * CC + ak * 4);
    float4 b0 = *(const float4*)(x + (size_t)bkr * HWSZ + nT + bn4 * 4);

    for (int kt = 0; kt < 14; ++kt) {
        {
            int kg = ak >> 1, jo = (ak & 1) * 4;
            us4 w;
            w = (us4){ f2b(a0.x), f2b(a0.y), f2b(a0.z), f2b(a0.w) };
            *(us4*)&As[kg * 1024 + (ar +  0) * 8 + jo] = w;
            w = (us4){ f2b(a1.x), f2b(a1.y), f2b(a1.z), f2b(a1.w) };
            *(us4*)&As[kg * 1024 + (ar + 32) * 8 + jo] = w;
            w = (us4){ f2b(a2.x), f2b(a2.y), f2b(a2.z), f2b(a2.w) };
            *(us4*)&As[kg * 1024 + (ar + 64) * 8 + jo] = w;
            w = (us4){ f2b(a3.x), f2b(a3.y), f2b(a3.z), f2b(a3.w) };
            *(us4*)&As[kg * 1024 + (ar + 96) * 8 + jo] = w;
            int base = (bkr >> 3) * 256 + bn4 * 32 + (bkr & 7);
            Bs[base]      = f2b(b0.x);
            Bs[base + 8]  = f2b(b0.y);
            Bs[base + 16] = f2b(b0.z);
            Bs[base + 24] = f2b(b0.w);
        }
        __syncthreads();
        // prefetch AFTER the barrier: its vmcnt drain lands at the NEXT
        // barrier, a full MFMA phase later (not immediately).
        if (kt < 13) {
            int ko = (kt + 1) * 32;
            a0 = *(const float4*)(Wk + (size_t)ar * CC + ko + ak * 4);
            a1 = *(const float4*)(Wk + (size_t)(ar + 32) * CC + ko + ak * 4);
            a2 = *(const float4*)(Wq + (size_t)ar * CC + ko + ak * 4);
            a3 = *(const float4*)(Wq + (size_t)(ar + 32) * CC + ko + ak * 4);
            b0 = *(const float4*)(x + (size_t)(ko + bkr) * HWSZ + nT + bn4 * 4);
        }
        short8 fa0 = *(short8*)&As[l4 * 1024 + (wm + l15) * 8];
        short8 fa1 = *(short8*)&As[l4 * 1024 + (wm + 16 + l15) * 8];
        short8 fb0 = *(short8*)&Bs[l4 * 256 + l15 * 8];
        short8 fb1 = *(short8*)&Bs[l4 * 256 + (16 + l15) * 8];
        acc[0][0] = __builtin_amdgcn_mfma_f32_16x16x32_bf16(fa0, fb0, acc[0][0], 0, 0, 0);
        acc[0][1] = __builtin_amdgcn_mfma_f32_16x16x32_bf16(fa0, fb1, acc[0][1], 0, 0, 0);
        acc[1][0] = __builtin_amdgcn_mfma_f32_16x16x32_bf16(fa1, fb0, acc[1][0], 0, 0, 0);
        acc[1][1] = __builtin_amdgcn_mfma_f32_16x16x32_bf16(fa1, fb1, acc[1][1], 0, 0, 0);
        __syncthreads();
    }
    const bool isK = (wid < 2);
    float*       Cd   = isK ? km : qm;
    const float* bias = isK ? bk : bq;
    const int rbase = (wm & 63);
    #pragma unroll
    for (int wm2 = 0; wm2 < 2; ++wm2)
        #pragma unroll
        for (int wn2 = 0; wn2 < 2; ++wn2)
            #pragma unroll
            for (int r = 0; r < 4; ++r) {
                int row = rbase + wm2 * 16 + l4 * 4 + r;
                int col = nT + wn2 * 16 + l15;
                Cd[(size_t)row * HWSZ + col] = acc[wm2][wn2][r] + bias[row];
            }
}

// ---------------- Kernel 3: fconv GEMM, 64x32 tiles, 896 blocks ----------
__global__ __launch_bounds__(256) void fconv_mfma(
    const float* __restrict__ pre,
    const float* __restrict__ Wf, const float* __restrict__ bfv,
    float* __restrict__ out)
{
    __shared__ unsigned short As[2048];   // 4 KB  [kg(4)][m(64)][j(8)]
    __shared__ unsigned short Bs[1024];   // 2 KB  [kg(4)][n(32)][j(8)]

    const int tid  = threadIdx.x;
    const int nT   = blockIdx.x * 32;
    const int oT   = blockIdx.y * 64;
    const int lane = tid & 63;
    const int wid  = tid >> 6;
    const int l15  = lane & 15;
    const int l4   = lane >> 4;

    const int ar = tid >> 3;
    const int ak = tid & 7;
    const int bkr = tid >> 3;
    const int bn4 = tid & 7;

    const float* __restrict__ A = Wf + (size_t)oT * CC;

    f32x4 acc[2];
    acc[0] = (f32x4){0.f, 0.f, 0.f, 0.f};
    acc[1] = (f32x4){0.f, 0.f, 0.f, 0.f};

    float4 a0 = *(const float4*)(A + (size_t)ar * CC + ak * 4);
    float4 a1 = *(const float4*)(A + (size_t)(ar + 32) * CC + ak * 4);
    float4 b0 = *(const float4*)(pre + (size_t)bkr * HWSZ + nT + bn4 * 4);

    for (int kt = 0; kt < 14; ++kt) {
        {
            int kg = ak >> 1, jo = (ak & 1) * 4;
            us4 w;
            w = (us4){ f2b(a0.x), f2b(a0.y), f2b(a0.z), f2b(a0.w) };
            *(us4*)&As[kg * 512 + (ar +  0) * 8 + jo] = w;
            w = (us4){ f2b(a1.x), f2b(a1.y), f2b(a1.z), f2b(a1.w) };
            *(us4*)&As[kg * 512 + (ar + 32) * 8 + jo] = w;
            int base = (bkr >> 3) * 256 + bn4 * 32 + (bkr & 7);
            Bs[base]      = f2b(b0.x);
            Bs[base + 8]  = f2b(b0.y);
            Bs[base + 16] = f2b(b0.z);
            Bs[base + 24] = f2b(b0.w);
        }
        __syncthreads();
        if (kt < 13) {
            int ko = (kt + 1) * 32;
            a0 = *(const float4*)(A + (size_t)ar * CC + ko + ak * 4);
            a1 = *(const float4*)(A + (size_t)(ar + 32) * CC + ko + ak * 4);
            b0 = *(const float4*)(pre + (size_t)(ko + bkr) * HWSZ + nT + bn4 * 4);
        }
        short8 fa  = *(short8*)&As[l4 * 512 + (wid * 16 + l15) * 8];
        short8 fb0 = *(short8*)&Bs[l4 * 256 + l15 * 8];
        short8 fb1 = *(short8*)&Bs[l4 * 256 + (16 + l15) * 8];
        acc[0] = __builtin_amdgcn_mfma_f32_16x16x32_bf16(fa, fb0, acc[0], 0, 0, 0);
        acc[1] = __builtin_amdgcn_mfma_f32_16x16x32_bf16(fa, fb1, acc[1], 0, 0, 0);
        __syncthreads();
    }
    #pragma unroll
    for (int wn2 = 0; wn2 < 2; ++wn2)
        #pragma unroll
        for (int r = 0; r < 4; ++r) {
            int row = oT + wid * 16 + l4 * 4 + r;
            int col = nT + wn2 * 16 + l15;
            out[(size_t)row * HWSZ + col] = acc[wn2][r] + bfv[row];
        }
}

// ---------------- Kernel 2: attention + aggregation (split-tap, spill-free) ----
#define GLO 196
#define GHI 260
#define XWORDS (GLO + HWSZ + GHI)   // 4552 words

__device__ __forceinline__ int win_off_global(int n, bool& ok) {
    int p  = n >> 12;
    int l  = n & 4095;
    int di = (p * 37) >> 8;    // p/7 exact for 0..48
    int dj = p - di * 7;
    int i  = (l >> 6) + di - 3;
    int j  = (l & 63) + dj - 3;
    ok = ((unsigned)i < 64u) && ((unsigned)j < 64u);
    return i * 64 + j;
}

// 512 threads = 8 waves. Waves 0-3 (half 0) own taps 0..24; waves 4-7 (half 1)
// own taps 25..48 of the SAME 256 lp. Each thread keeps only w[25] -> no spills.
// Softmax max/denom and per-m partial sums combined via small LDS reductions
// (wave-uniform half branch: no divergence).
__global__ __launch_bounds__(512) void attn_kernel(
    const float* __restrict__ km, const float* __restrict__ qm,
    const float* __restrict__ x,
    const float* __restrict__ gw1, const float* __restrict__ gb1,
    const float* __restrict__ gw2, const float* __restrict__ gb2,
    float* __restrict__ pre)
{
    __shared__ float klin[XWORDS];
    __shared__ float xlin[XWORDS];
    __shared__ float gpk_s[KK2];
    __shared__ float red[2][256];

    const int tid  = threadIdx.x;
    const int lane = tid & 63;
    const int wid  = tid >> 6;          // 0..7
    const int half = wid >> 2;          // 0 or 1
    const int lpi  = (wid & 3) * 64 + lane;   // 0..255
    const int g    = blockIdx.y;
    const int lp   = blockIdx.x * 256 + lpi;

    // zero guard bands: lo 49 float4, hi 65 float4 each
    if (tid < 114) {
        float4 z = {0.f, 0.f, 0.f, 0.f};
        int w = (tid < 49) ? tid * 4 : (GLO + HWSZ + (tid - 49) * 4);
        *(float4*)&klin[w] = z;
        *(float4*)&xlin[w] = z;
    }
    // stage km page: 1024 float4 over 512 threads
    {
        const float4* km4 = (const float4*)(km + (size_t)g * HWSZ);
        *(float4*)&klin[GLO + tid * 4]         = km4[tid];
        *(float4*)&klin[GLO + (tid + 512) * 4] = km4[tid + 512];
    }
    // fused geometry prior: row g (49 values)
    if (tid < KK2) {
        int di = tid / 7, dj = tid - di * 7;
        float xp = (float)(dj - 3);
        float yp = (float)(3 - di);
        float acc = gb2[g];
        #pragma unroll
        for (int j = 0; j < GPH; ++j) {
            float h = gw1[j * 2 + 0] * xp + gw1[j * 2 + 1] * yp + gb1[j];
            h = fmaxf(h, 0.f);
            acc = fmaf(gw2[g * GPH + j], h, acc);
        }
        gpk_s[tid] = acc;
    }

    // q center
    float qc;
    { bool ok; int o = win_off_global(lp * KK2 + 24, ok); qc = ok ? qm[(size_t)g * HWSZ + o] : 0.f; }

    // per-thread segment constants (taps contiguous in <=2 segments)
    const int n0 = lp * KK2;
    const int p0 = n0 >> 12;
    const int l0 = n0 & 4095;
    const int ts = ((p0 + 1) << 12) - n0;
    const int di0 = (p0 * 37) >> 8, dj0 = p0 - di0 * 7;
    const int p1  = p0 + 1;
    const int di1 = (p1 * 37) >> 8, dj1 = p1 - di1 * 7;
    const int djm3_0 = dj0 - 3, djm3_1 = dj1 - 3;
    const int B0 = GLO + l0 + (di0 - 3) * 64 + djm3_0;
    const int B1 = GLO + l0 - 4096 + (di1 - 3) * 64 + djm3_1;

    // prefetch m=0 x page
    float4 xr0, xr1;
    {
        const float4* xg4 = (const float4*)(x + (size_t)g * HWSZ);
        xr0 = xg4[tid]; xr1 = xg4[tid + 512];
    }
    __syncthreads();   // staging done (drains prefetch too; one-time cost)

    // Phase A: logits for this half's taps
    float w[25];
    float mx = -1e30f;
#define LOGIT(T, I) { \
        bool s1 = ((T) >= ts); \
        int base = s1 ? B1 : B0; \
        float kv = klin[base + (T)]; \
        int jj = ((l0 + (T)) & 63) + (s1 ? djm3_1 : djm3_0); \
        kv = ((unsigned)jj < 64u) ? kv : 0.f; \
        float av = fmaf(kv, qc, gpk_s[(T)]); \
        w[(I)] = av; mx = fmaxf(mx, av); }
    if (half == 0) {
        #pragma unroll
        for (int t = 0; t < 25; ++t) LOGIT(t, t)
    } else {
        #pragma unroll
        for (int t = 25; t < 49; ++t) LOGIT(t, t - 25)
    }
#undef LOGIT
    red[half][lpi] = mx;
    __syncthreads();
    mx = fmaxf(mx, red[1 - half][lpi]);

    float d = 0.f;
#define EXPW(T, I) { \
        float e = __expf(w[(I)] - mx); \
        d += e; \
        bool s1 = ((T) >= ts); \
        int jj = ((l0 + (T)) & 63) + (s1 ? djm3_1 : djm3_0); \
        w[(I)] = ((unsigned)jj < 64u) ? e : 0.f; }
    if (half == 0) {
        #pragma unroll
        for (int t = 0; t < 25; ++t) EXPW(t, t)
    } else {
        #pragma unroll
        for (int t = 25; t < 49; ++t) EXPW(t, t - 25)
    }
#undef EXPW
    __syncthreads();               // max reads done before overwriting red
    red[half][lpi] = d;
    __syncthreads();
    const float inv = 1.f / (d + red[1 - half][lpi]);

    // Phase B: per m, write staged page, compute half-partials, combine
    #pragma unroll 1
    for (int m = 0; m < MMM; ++m) {
        __syncthreads();           // xlin readers + red consumers of m-1 done
        *(float4*)&xlin[GLO + tid * 4]         = xr0;
        *(float4*)&xlin[GLO + (tid + 512) * 4] = xr1;
        __syncthreads();           // xlin ready
        if (m < MMM - 1) {         // prefetch AFTER barrier: drain lands next iter
            const float4* xg4 = (const float4*)(x + (size_t)((m + 1) * CGC + g) * HWSZ);
            xr0 = xg4[tid]; xr1 = xg4[tid + 512];
        }
        float part = 0.f;
        if (half == 0) {
            #pragma unroll
            for (int t = 0; t < 25; ++t) {
                int base = (t >= ts) ? B1 : B0;
                part = fmaf(w[t], xlin[base + t], part);
            }
        } else {
            #pragma unroll
            for (int t = 25; t < 49; ++t) {
                int base = (t >= ts) ? B1 : B0;
                part = fmaf(w[t - 25], xlin[base + t], part);
            }
        }
        if (half == 1) red[1][lpi] = part;
        __syncthreads();
        if (half == 0)
            pre[(size_t)(m * CGC + g) * HWSZ + lp] = (part + red[1][lpi]) * inv;
    }
}

extern "C" void kernel_launch(void* const* d_in, const int* in_sizes, int n_in,
                              void* d_out, int out_size, void* d_ws, size_t ws_size,
                              hipStream_t stream) {
    const float* x   = (const float*)d_in[0];
    const float* Wk  = (const float*)d_in[1];
    const float* bk  = (const float*)d_in[2];
    const float* Wq  = (const float*)d_in[3];
    const float* bq  = (const float*)d_in[4];
    const float* gw1 = (const float*)d_in[5];
    const float* gb1 = (const float*)d_in[6];
    const float* gw2 = (const float*)d_in[7];
    const float* gb2 = (const float*)d_in[8];
    const float* Wf  = (const float*)d_in[9];
    const float* bfv = (const float*)d_in[10];
    float* out = (float*)d_out;

    float* km  = (float*)d_ws;             // 64*4096
    float* qm  = km + CGC * HWSZ;          // 64*4096
    float* pre = qm + CGC * HWSZ;          // 448*4096

    kq_mfma    <<<dim3(128),     256, 0, stream>>>(x, Wk, bk, Wq, bq, km, qm);
    attn_kernel<<<dim3(16, CGC), 512, 0, stream>>>(km, qm, x, gw1, gb1, gw2, gb2, pre);
    fconv_mfma <<<dim3(128, 7),  256, 0, stream>>>(pre, Wf, bfv, out);
}

// Round 9
// 116.104 us; speedup vs baseline: 1.1462x; 1.1462x over previous
//
#include <hip/hip_runtime.h>
#include <hip/hip_bf16.h>

// Problem constants (B=1)
#define CC   448   // channels
#define CGC  64    // key/query channels
#define MMM  7     // m groups
#define HWSZ 4096  // H*W
#define KK2  49    // K*K
#define GPH  32    // geometry-prior hidden

typedef __attribute__((ext_vector_type(8))) short   short8;   // 8 bf16 (4 VGPRs)
typedef __attribute__((ext_vector_type(4))) float   f32x4;
typedef __attribute__((ext_vector_type(4))) unsigned short us4;

__device__ __forceinline__ unsigned short f2b(float f) {
    union { __hip_bfloat16 h; unsigned short u; } cv;
    cv.h = __float2bfloat16(f);
    return cv.u;
}

// ---------------- Kernel 1: fused k+q GEMM (R7 config: best measured) ----
// C[128, 4096] = [Wk;Wq](128x448) @ x(448x4096). Tile 128x32, 256 thr = 4 waves.
__global__ __launch_bounds__(256) void kq_mfma(
    const float* __restrict__ x,
    const float* __restrict__ Wk, const float* __restrict__ bk,
    const float* __restrict__ Wq, const float* __restrict__ bq,
    float* __restrict__ km, float* __restrict__ qm)
{
    __shared__ unsigned short As[4096];   // 8 KB  [kg(4)][m(128)][j(8)]
    __shared__ unsigned short Bs[1024];   // 2 KB  [kg(4)][n(32)][j(8)]

    const int tid  = threadIdx.x;
    const int nT   = blockIdx.x * 32;
    const int lane = tid & 63;
    const int wid  = tid >> 6;
    const int wm   = wid * 32;
    const int l15  = lane & 15;
    const int l4   = lane >> 4;

    const int ar = tid >> 3;          // 0..31: A row within rep
    const int ak = tid & 7;           // which float4 of the 32-k chunk
    const int bkr = tid >> 3;         // 0..31: B k-row
    const int bn4 = tid & 7;          // 0..7: B float4 col group

    f32x4 acc[2][2];
    #pragma unroll
    for (int i = 0; i < 2; ++i)
        #pragma unroll
        for (int j = 0; j < 2; ++j)
            acc[i][j] = (f32x4){0.f, 0.f, 0.f, 0.f};

    float4 a0 = *(const float4*)(Wk + (size_t)ar * CC + ak * 4);
    float4 a1 = *(const float4*)(Wk + (size_t)(ar + 32) * CC + ak * 4);
    float4 a2 = *(const float4*)(Wq + (size_t)ar * CC + ak * 4);
    float4 a3 = *(const float4*)(Wq + (size_t)(ar + 32) * CC + ak * 4);
    float4 b0 = *(const float4*)(x + (size_t)bkr * HWSZ + nT + bn4 * 4);

    for (int kt = 0; kt < 14; ++kt) {
        {
            int kg = ak >> 1, jo = (ak & 1) * 4;
            us4 w;
            w = (us4){ f2b(a0.x), f2b(a0.y), f2b(a0.z), f2b(a0.w) };
            *(us4*)&As[kg * 1024 + (ar +  0) * 8 + jo] = w;
            w = (us4){ f2b(a1.x), f2b(a1.y), f2b(a1.z), f2b(a1.w) };
            *(us4*)&As[kg * 1024 + (ar + 32) * 8 + jo] = w;
            w = (us4){ f2b(a2.x), f2b(a2.y), f2b(a2.z), f2b(a2.w) };
            *(us4*)&As[kg * 1024 + (ar + 64) * 8 + jo] = w;
            w = (us4){ f2b(a3.x), f2b(a3.y), f2b(a3.z), f2b(a3.w) };
            *(us4*)&As[kg * 1024 + (ar + 96) * 8 + jo] = w;
            int base = (bkr >> 3) * 256 + bn4 * 32 + (bkr & 7);
            Bs[base]      = f2b(b0.x);
            Bs[base + 8]  = f2b(b0.y);
            Bs[base + 16] = f2b(b0.z);
            Bs[base + 24] = f2b(b0.w);
        }
        if (kt < 13) {
            int ko = (kt + 1) * 32;
            a0 = *(const float4*)(Wk + (size_t)ar * CC + ko + ak * 4);
            a1 = *(const float4*)(Wk + (size_t)(ar + 32) * CC + ko + ak * 4);
            a2 = *(const float4*)(Wq + (size_t)ar * CC + ko + ak * 4);
            a3 = *(const float4*)(Wq + (size_t)(ar + 32) * CC + ko + ak * 4);
            b0 = *(const float4*)(x + (size_t)(ko + bkr) * HWSZ + nT + bn4 * 4);
        }
        __syncthreads();
        short8 fa0 = *(short8*)&As[l4 * 1024 + (wm + l15) * 8];
        short8 fa1 = *(short8*)&As[l4 * 1024 + (wm + 16 + l15) * 8];
        short8 fb0 = *(short8*)&Bs[l4 * 256 + l15 * 8];
        short8 fb1 = *(short8*)&Bs[l4 * 256 + (16 + l15) * 8];
        acc[0][0] = __builtin_amdgcn_mfma_f32_16x16x32_bf16(fa0, fb0, acc[0][0], 0, 0, 0);
        acc[0][1] = __builtin_amdgcn_mfma_f32_16x16x32_bf16(fa0, fb1, acc[0][1], 0, 0, 0);
        acc[1][0] = __builtin_amdgcn_mfma_f32_16x16x32_bf16(fa1, fb0, acc[1][0], 0, 0, 0);
        acc[1][1] = __builtin_amdgcn_mfma_f32_16x16x32_bf16(fa1, fb1, acc[1][1], 0, 0, 0);
        __syncthreads();
    }
    const bool isK = (wid < 2);
    float*       Cd   = isK ? km : qm;
    const float* bias = isK ? bk : bq;
    const int rbase = (wm & 63);
    #pragma unroll
    for (int wm2 = 0; wm2 < 2; ++wm2)
        #pragma unroll
        for (int wn2 = 0; wn2 < 2; ++wn2)
            #pragma unroll
            for (int r = 0; r < 4; ++r) {
                int row = rbase + wm2 * 16 + l4 * 4 + r;
                int col = nT + wn2 * 16 + l15;
                Cd[(size_t)row * HWSZ + col] = acc[wm2][wn2][r] + bias[row];
            }
}

// ---------------- Kernel 3: fconv GEMM, 64x32 tiles (R7 config) ----------
__global__ __launch_bounds__(256) void fconv_mfma(
    const float* __restrict__ pre,
    const float* __restrict__ Wf, const float* __restrict__ bfv,
    float* __restrict__ out)
{
    __shared__ unsigned short As[2048];   // 4 KB  [kg(4)][m(64)][j(8)]
    __shared__ unsigned short Bs[1024];   // 2 KB  [kg(4)][n(32)][j(8)]

    const int tid  = threadIdx.x;
    const int nT   = blockIdx.x * 32;
    const int oT   = blockIdx.y * 64;
    const int lane = tid & 63;
    const int wid  = tid >> 6;
    const int l15  = lane & 15;
    const int l4   = lane >> 4;

    const int ar = tid >> 3;
    const int ak = tid & 7;
    const int bkr = tid >> 3;
    const int bn4 = tid & 7;

    const float* __restrict__ A = Wf + (size_t)oT * CC;

    f32x4 acc[2];
    acc[0] = (f32x4){0.f, 0.f, 0.f, 0.f};
    acc[1] = (f32x4){0.f, 0.f, 0.f, 0.f};

    float4 a0 = *(const float4*)(A + (size_t)ar * CC + ak * 4);
    float4 a1 = *(const float4*)(A + (size_t)(ar + 32) * CC + ak * 4);
    float4 b0 = *(const float4*)(pre + (size_t)bkr * HWSZ + nT + bn4 * 4);

    for (int kt = 0; kt < 14; ++kt) {
        {
            int kg = ak >> 1, jo = (ak & 1) * 4;
            us4 w;
            w = (us4){ f2b(a0.x), f2b(a0.y), f2b(a0.z), f2b(a0.w) };
            *(us4*)&As[kg * 512 + (ar +  0) * 8 + jo] = w;
            w = (us4){ f2b(a1.x), f2b(a1.y), f2b(a1.z), f2b(a1.w) };
            *(us4*)&As[kg * 512 + (ar + 32) * 8 + jo] = w;
            int base = (bkr >> 3) * 256 + bn4 * 32 + (bkr & 7);
            Bs[base]      = f2b(b0.x);
            Bs[base + 8]  = f2b(b0.y);
            Bs[base + 16] = f2b(b0.z);
            Bs[base + 24] = f2b(b0.w);
        }
        if (kt < 13) {
            int ko = (kt + 1) * 32;
            a0 = *(const float4*)(A + (size_t)ar * CC + ko + ak * 4);
            a1 = *(const float4*)(A + (size_t)(ar + 32) * CC + ko + ak * 4);
            b0 = *(const float4*)(pre + (size_t)(ko + bkr) * HWSZ + nT + bn4 * 4);
        }
        __syncthreads();
        short8 fa  = *(short8*)&As[l4 * 512 + (wid * 16 + l15) * 8];
        short8 fb0 = *(short8*)&Bs[l4 * 256 + l15 * 8];
        short8 fb1 = *(short8*)&Bs[l4 * 256 + (16 + l15) * 8];
        acc[0] = __builtin_amdgcn_mfma_f32_16x16x32_bf16(fa, fb0, acc[0], 0, 0, 0);
        acc[1] = __builtin_amdgcn_mfma_f32_16x16x32_bf16(fa, fb1, acc[1], 0, 0, 0);
        __syncthreads();
    }
    #pragma unroll
    for (int wn2 = 0; wn2 < 2; ++wn2)
        #pragma unroll
        for (int r = 0; r < 4; ++r) {
            int row = oT + wid * 16 + l4 * 4 + r;
            int col = nT + wn2 * 16 + l15;
            out[(size_t)row * HWSZ + col] = acc[wn2][r] + bfv[row];
        }
}

// ---------------- Kernel 2: attention, double-buffered x pages -----------
#define GLO 196
#define GHI 260
#define XWORDS (GLO + HWSZ + GHI)   // 4552 words

__device__ __forceinline__ int win_off_global(int n, bool& ok) {
    int p  = n >> 12;
    int l  = n & 4095;
    int di = (p * 37) >> 8;    // p/7 exact for 0..48
    int dj = p - di * 7;
    int i  = (l >> 6) + di - 3;
    int j  = (l & 63) + dj - 3;
    ok = ((unsigned)i < 64u) && ((unsigned)j < 64u);
    return i * 64 + j;
}

// 256 thr, one g, 256 lp. klin + 2 x-page buffers = 54.8 KB -> 2 blocks/CU.
// Per m-iteration: ONE barrier; page m+1 global loads issue before the 49-tap
// loop (latency hidden by compute), land in the alternate buffer after it.
__global__ __launch_bounds__(256, 2) void attn_kernel(
    const float* __restrict__ km, const float* __restrict__ qm,
    const float* __restrict__ x,
    const float* __restrict__ gw1, const float* __restrict__ gb1,
    const float* __restrict__ gw2, const float* __restrict__ gb2,
    float* __restrict__ pre)
{
    __shared__ float klin[XWORDS];
    __shared__ float xbuf[2][XWORDS];
    __shared__ float gpk_s[KK2];
    const int tid = threadIdx.x;
    const int g   = blockIdx.y;
    const int lp  = blockIdx.x * 256 + tid;

    // zero guard bands (lo 49 float4, hi 65 float4) of all three arrays
    if (tid < 114) {
        float4 z = {0.f, 0.f, 0.f, 0.f};
        int w = (tid < 49) ? tid * 4 : (GLO + HWSZ + (tid - 49) * 4);
        *(float4*)&klin[w]    = z;
        *(float4*)&xbuf[0][w] = z;
        *(float4*)&xbuf[1][w] = z;
    }
    // stage km page + x page 0 (4 float4 each per thread, coalesced)
    {
        const float4* km4 = (const float4*)(km + (size_t)g * HWSZ);
        const float4* xg4 = (const float4*)(x + (size_t)g * HWSZ);
        #pragma unroll
        for (int i = 0; i < 4; ++i) {
            int idx = tid + i * 256;
            *(float4*)&klin[GLO + idx * 4]    = km4[idx];
            *(float4*)&xbuf[0][GLO + idx * 4] = xg4[idx];
        }
    }
    // fused geometry prior: row g (49 values)
    if (tid < KK2) {
        int di = tid / 7, dj = tid - di * 7;
        float xp = (float)(dj - 3);
        float yp = (float)(3 - di);
        float acc = gb2[g];
        #pragma unroll
        for (int j = 0; j < GPH; ++j) {
            float h = gw1[j * 2 + 0] * xp + gw1[j * 2 + 1] * yp + gb1[j];
            h = fmaxf(h, 0.f);
            acc = fmaf(gw2[g * GPH + j], h, acc);
        }
        gpk_s[tid] = acc;
    }

    // q center
    float qc;
    { bool ok; int o = win_off_global(lp * KK2 + 24, ok); qc = ok ? qm[(size_t)g * HWSZ + o] : 0.f; }

    // per-thread segment constants (taps contiguous in <=2 segments)
    const int n0 = lp * KK2;
    const int p0 = n0 >> 12;
    const int l0 = n0 & 4095;
    const int ts = ((p0 + 1) << 12) - n0;
    const int di0 = (p0 * 37) >> 8, dj0 = p0 - di0 * 7;
    const int p1  = p0 + 1;
    const int di1 = (p1 * 37) >> 8, dj1 = p1 - di1 * 7;
    const int djm3_0 = dj0 - 3, djm3_1 = dj1 - 3;
    const int B0 = GLO + l0 + (di0 - 3) * 64 + djm3_0;
    const int B1 = GLO + l0 - 4096 + (di1 - 3) * 64 + djm3_1;
    __syncthreads();   // klin/xbuf[0]/guards/gpk staged

    // Phase A: logits
    float a[KK2];
    float mx = -1e30f;
    #pragma unroll
    for (int t = 0; t < KK2; ++t) {
        bool s1 = (t >= ts);
        int base = s1 ? B1 : B0;
        float kv = klin[base + t];
        int jj = ((l0 + t) & 63) + (s1 ? djm3_1 : djm3_0);
        kv = ((unsigned)jj < 64u) ? kv : 0.f;
        float av = fmaf(kv, qc, gpk_s[t]);
        a[t] = av;
        mx = fmaxf(mx, av);
    }
    float d = 0.f;
    #pragma unroll
    for (int t = 0; t < KK2; ++t) {
        float e = __expf(a[t] - mx);
        d += e;                                  // padded taps count in denominator
        bool s1 = (t >= ts);
        int jj = ((l0 + t) & 63) + (s1 ? djm3_1 : djm3_0);
        a[t] = ((unsigned)jj < 64u) ? e : 0.f;
    }
    const float inv = 1.f / d;

    // Phase B: double-buffered, one barrier per m
    #pragma unroll 1
    for (int m = 0; m < MMM; ++m) {
        const float* __restrict__ cur = xbuf[m & 1];
        float4 xr0, xr1, xr2, xr3;
        if (m < MMM - 1) {   // issue early: latency hidden by tap loop below
            const float4* xn = (const float4*)(x + (size_t)((m + 1) * CGC + g) * HWSZ);
            xr0 = xn[tid]; xr1 = xn[tid + 256]; xr2 = xn[tid + 512]; xr3 = xn[tid + 768];
        }
        float acc = 0.f;
        #pragma unroll
        for (int t = 0; t < KK2; ++t) {
            int base = (t >= ts) ? B1 : B0;
            acc = fmaf(a[t], cur[base + t], acc);
        }
        pre[(size_t)(m * CGC + g) * HWSZ + lp] = acc * inv;
        if (m < MMM - 1) {   // alt buffer: its m-1 readers passed the last barrier
            float* __restrict__ nxt = xbuf[1 - (m & 1)];
            *(float4*)&nxt[GLO + tid * 4]          = xr0;
            *(float4*)&nxt[GLO + (tid + 256) * 4]  = xr1;
            *(float4*)&nxt[GLO + (tid + 512) * 4]  = xr2;
            *(float4*)&nxt[GLO + (tid + 768) * 4]  = xr3;
        }
        __syncthreads();
    }
}

extern "C" void kernel_launch(void* const* d_in, const int* in_sizes, int n_in,
                              void* d_out, int out_size, void* d_ws, size_t ws_size,
                              hipStream_t stream) {
    const float* x   = (const float*)d_in[0];
    const float* Wk  = (const float*)d_in[1];
    const float* bk  = (const float*)d_in[2];
    const float* Wq  = (const float*)d_in[3];
    const float* bq  = (const float*)d_in[4];
    const float* gw1 = (const float*)d_in[5];
    const float* gb1 = (const float*)d_in[6];
    const float* gw2 = (const float*)d_in[7];
    const float* gb2 = (const float*)d_in[8];
    const float* Wf  = (const float*)d_in[9];
    const float* bfv = (const float*)d_in[10];
    float* out = (float*)d_out;

    float* km  = (float*)d_ws;             // 64*4096
    float* qm  = km + CGC * HWSZ;          // 64*4096
    float* pre = qm + CGC * HWSZ;          // 448*4096

    kq_mfma    <<<dim3(128),     256, 0, stream>>>(x, Wk, bk, Wq, bq, km, qm);
    attn_kernel<<<dim3(16, CGC), 256, 0, stream>>>(km, qm, x, gw1, gb1, gw2, gb2, pre);
    fconv_mfma <<<dim3(128, 7),  256, 0, stream>>>(pre, Wf, bfv, out);
}